// Round 5
// baseline (719.830 us; speedup 1.0000x reference)
//
#include <hip/hip_runtime.h>
#include <cstdint>
#include <cstddef>

using bf16x8 = __attribute__((ext_vector_type(8))) short;
using f32x4  = __attribute__((ext_vector_type(4))) float;

constexpr int kB = 8192;
constexpr int kD = 1024;
constexpr int kE = 8;
constexpr int kH = 4096;
constexpr int kC = 10;

__device__ __forceinline__ unsigned short f2bf(float f) {
  unsigned int u = __float_as_uint(f);
  u += 0x7FFFu + ((u >> 16) & 1u);   // round-to-nearest-even (finite inputs)
  return (unsigned short)(u >> 16);
}

#define GLD16(gptr, lptr)                                                      \
  __builtin_amdgcn_global_load_lds(                                            \
      (const __attribute__((address_space(1))) void*)(gptr),                   \
      (__attribute__((address_space(3))) void*)(lptr), 16, 0, 0)

// ---------------- convert x: f32 -> bf16, 8 elems/thread ----------------
__global__ __launch_bounds__(256) void k_convert_x(const float* __restrict__ x,
                                                   unsigned short* __restrict__ xb) {
  const long i = ((long)blockIdx.x * 256 + threadIdx.x) * 8;
  float4 a = *reinterpret_cast<const float4*>(x + i);
  float4 b = *reinterpret_cast<const float4*>(x + i + 4);
  bf16x8 o;
  o[0] = (short)f2bf(a.x); o[1] = (short)f2bf(a.y);
  o[2] = (short)f2bf(a.z); o[3] = (short)f2bf(a.w);
  o[4] = (short)f2bf(b.x); o[5] = (short)f2bf(b.y);
  o[6] = (short)f2bf(b.z); o[7] = (short)f2bf(b.w);
  *reinterpret_cast<bf16x8*>(xb + i) = o;
}

// ------------- transpose+convert W1 [E][D][H] f32 -> W1t [E][H][D] bf16 -------------
__global__ __launch_bounds__(256) void k_transpose_w(const float* __restrict__ W,
                                                     unsigned short* __restrict__ Wt,
                                                     int K, int N) {
  __shared__ unsigned short tile[32][33];
  const int e = blockIdx.z;
  const int n0 = blockIdx.x * 32, k0 = blockIdx.y * 32;
  const int tx = threadIdx.x, ty = threadIdx.y;  // (32,8)
  const float* Wb = W + (size_t)e * K * N;
  unsigned short* Wtb = Wt + (size_t)e * N * K;
#pragma unroll
  for (int j = 0; j < 32; j += 8)
    tile[ty + j][tx] = f2bf(Wb[(size_t)(k0 + ty + j) * N + n0 + tx]);
  __syncthreads();
#pragma unroll
  for (int j = 0; j < 32; j += 8)
    Wtb[(size_t)(n0 + ty + j) * K + k0 + tx] = tile[tx][ty + j];
}

// ---------------- routing: softmax(x @ Wr + br), one wave per row ----------------
__global__ __launch_bounds__(256) void k_routing(const float* __restrict__ x,
                                                 const float* __restrict__ Wr,
                                                 const float* __restrict__ br,
                                                 float* __restrict__ r) {
  const int w = threadIdx.x >> 6, l = threadIdx.x & 63;
  const int b = blockIdx.x * 4 + w;
  const float* xr = x + (size_t)b * kD;
  float acc[kE];
#pragma unroll
  for (int e = 0; e < kE; ++e) acc[e] = 0.f;
  for (int d = l; d < kD; d += 64) {
    const float xv = xr[d];
    const float* wrow = Wr + d * kE;
#pragma unroll
    for (int e = 0; e < kE; ++e) acc[e] += xv * wrow[e];
  }
#pragma unroll
  for (int e = 0; e < kE; ++e) {
#pragma unroll
    for (int s = 32; s > 0; s >>= 1) acc[e] += __shfl_xor(acc[e], s);
    acc[e] += br[e];
  }
  float mx = acc[0];
#pragma unroll
  for (int e = 1; e < kE; ++e) mx = fmaxf(mx, acc[e]);
  float sum = 0.f;
#pragma unroll
  for (int e = 0; e < kE; ++e) { acc[e] = expf(acc[e] - mx); sum += acc[e]; }
  const float inv = 1.f / sum;
  float val = 0.f;
#pragma unroll
  for (int e = 0; e < kE; ++e) if (l == e) val = acc[e] * inv;
  if (l < kE) r[(size_t)b * kE + l] = val;
}

// ------- V-build: Vt[e][c][h] = sum_d W2[e][h][d]*Wc[d][c]; rows c>=10 zeroed -------
__global__ __launch_bounds__(128) void k_vbuild(const float* __restrict__ W2,
                                                const float* __restrict__ Wc,
                                                unsigned short* __restrict__ Vt) {
  __shared__ float WcL[kD * kC];  // 40 KB
  for (int i = threadIdx.x; i < kD * kC; i += 128) WcL[i] = Wc[i];
  __syncthreads();
  const int gid = blockIdx.x * 128 + threadIdx.x;  // e*4096 + h
  const int e = gid >> 12, hrow = gid & 4095;
  const float4* w2row = reinterpret_cast<const float4*>(W2 + (size_t)gid * kD);
  float acc[kC];
#pragma unroll
  for (int c = 0; c < kC; ++c) acc[c] = 0.f;
  for (int i = 0; i < kD / 4; ++i) {
    float4 w = w2row[i];
    const float* wc0 = WcL + (i * 4) * kC;
#pragma unroll
    for (int c = 0; c < kC; ++c)
      acc[c] += w.x * wc0[c] + w.y * wc0[kC + c] + w.z * wc0[2 * kC + c] +
                w.w * wc0[3 * kC + c];
  }
  unsigned short* vte = Vt + (size_t)e * 16 * kH;
#pragma unroll
  for (int c = 0; c < kC; ++c) vte[(size_t)c * kH + hrow] = f2bf(acc[c]);
#pragma unroll
  for (int c = kC; c < 16; ++c) vte[(size_t)c * kH + hrow] = 0;
}

// ------- u-build: u[e][c] = sum_d b2[e][d] * Wc[d][c] -------
__global__ __launch_bounds__(128) void k_ubuild(const float* __restrict__ b2,
                                                const float* __restrict__ Wc,
                                                float* __restrict__ u) {
  const int t = threadIdx.x;
  if (t >= kE * kC) return;
  const int e = t / kC, c = t % kC;
  float acc = 0.f;
  for (int d = 0; d < kD; ++d) acc += b2[e * kD + d] * Wc[d * kC + c];
  u[e * 16 + c] = acc;
}

__global__ __launch_bounds__(256) void k_zero_f32(float* __restrict__ p) {
  p[(size_t)blockIdx.x * 256 + threadIdx.x] = 0.f;
}

// ============================================================================
// fused 256x256 8-phase GEMM1 + V-contraction, with one-phase-ahead
// register prefetch (counted lgkmcnt) so ds_read latency hides under MFMA.
//   part[b][c] += r[b,e] * sum_h relu(x@W1[e]+b1[e])[b,h] * Vt[e][c][h]
// ============================================================================
__global__ __launch_bounds__(512, 2) void k_moe_fused256(
    const unsigned short* __restrict__ xb,   // [B][D] bf16
    const unsigned short* __restrict__ W1t,  // [E][H][D] bf16
    const float* __restrict__ b1,            // [E][H]
    const unsigned short* __restrict__ Vt,   // [E][16][H] bf16
    const float* __restrict__ rr,            // [B][E]
    float* __restrict__ part) {              // [B][16] f32 (atomic accum)
  __shared__ __align__(16) char smem[131072];
  constexpr int K = kD;          // 1024
  constexpr int NIT = K / 128;   // 8 iterations, 2 K-tiles (BK=64) each

  const int e = blockIdx.z;
  const int bx = (blockIdx.x & 7) * 4 + (blockIdx.x >> 3);  // bijective XCD swizzle (32%8==0)
  const int brow = bx * 256, bcol = blockIdx.y * 256;
  const unsigned short* const At = xb;
  const unsigned short* const Bt = W1t + (size_t)e * kH * kD;

  const int tid = threadIdx.x;
  const int w = tid >> 6, l = tid & 63;
  const int wr = w >> 2, wc = w & 3;       // wave grid 2M x 4N
  const int fr = l & 15, jg = l >> 4;      // fragment row / k-chunk group

  // fragment-read swizzled chunk offsets (row&7 == fr&7 since all row bases %16==0)
  int ck[2];
#pragma unroll
  for (int k = 0; k < 2; ++k) ck[k] = (((k * 4 + jg) ^ (fr & 7)) << 4);
  const int abase = wr * 16384;                 // + buf*65536           (A region)
  const int bbase = 32768 + (wc >> 1) * 16384;  // + buf*65536           (B region)
  const int brow0 = (wc & 1) * 64;              // B row base within half

  // staging: linear LDS dest, inverse-swizzled global source (rule 21)
  const int p0 = w * 64 + l;            // phys 16B chunk within an 8KB round
  const int rp = p0 >> 3;               // row 0..63 (round 0); +64 for round 1
  const int cs = (p0 & 7) ^ (rp & 7);   // logical chunk (same both rounds)
  const size_t aofs = (size_t)(brow + rp) * K + cs * 8;
  const size_t bofs = (size_t)(bcol + rp) * K + cs * 8;
  const int ldst = w * 1024;            // wave-uniform LDS dest offset

#define STG_A(buf, ht, kt)                                                     \
  do {                                                                         \
    GLD16(At + aofs + (size_t)(ht) * 131072 + (size_t)(kt) * 64,               \
          smem + (buf) * 65536 + (ht) * 16384 + ldst);                         \
    GLD16(At + aofs + (size_t)(ht) * 131072 + 65536 + (size_t)(kt) * 64,       \
          smem + (buf) * 65536 + (ht) * 16384 + 8192 + ldst);                  \
  } while (0)
#define STG_B(buf, ht, kt)                                                     \
  do {                                                                         \
    GLD16(Bt + bofs + (size_t)(ht) * 131072 + (size_t)(kt) * 64,               \
          smem + (buf) * 65536 + 32768 + (ht) * 16384 + ldst);                 \
    GLD16(Bt + bofs + (size_t)(ht) * 131072 + 65536 + (size_t)(kt) * 64,       \
          smem + (buf) * 65536 + 32768 + (ht) * 16384 + 8192 + ldst);          \
  } while (0)

// prefetch phase reads into a NAMED register set (static indexing, rule #20)
#define PREF_A(buf, mp, SET)                                                   \
  do {                                                                         \
    _Pragma("unroll") for (int mm = 0; mm < 2; ++mm)                           \
    _Pragma("unroll") for (int k = 0; k < 2; ++k)                              \
      SET[mm][k] = *reinterpret_cast<const bf16x8*>(                           \
          smem + (buf) * 65536 + abase + (((mp) * 2 + mm) * 16 + fr) * 128 + ck[k]); \
  } while (0)
#define PREF_B(buf, SET)                                                       \
  do {                                                                         \
    _Pragma("unroll") for (int n = 0; n < 4; ++n)                              \
    _Pragma("unroll") for (int k = 0; k < 2; ++k)                              \
      SET[n][k] = *reinterpret_cast<const bf16x8*>(                            \
          smem + (buf) * 65536 + bbase + (brow0 + n * 16 + fr) * 128 + ck[k]); \
  } while (0)
#define MFMA16(AQ, BQ, mp)                                                     \
  do {                                                                         \
    __builtin_amdgcn_s_setprio(1);                                             \
    _Pragma("unroll") for (int mm = 0; mm < 2; ++mm)                           \
    _Pragma("unroll") for (int n = 0; n < 4; ++n)                              \
    _Pragma("unroll") for (int k = 0; k < 2; ++k)                              \
      acc[(mp) * 2 + mm][n] = __builtin_amdgcn_mfma_f32_16x16x32_bf16(         \
          AQ[mm][k], BQ[n][k], acc[(mp) * 2 + mm][n], 0, 0, 0);                \
    __builtin_amdgcn_s_setprio(0);                                             \
  } while (0)
#define BAR()    asm volatile("s_barrier" ::: "memory")
#define SCB()    __builtin_amdgcn_sched_barrier(0)
#define WAITL(n) do { asm volatile("s_waitcnt lgkmcnt(" #n ")" ::: "memory"); SCB(); } while (0)
#define WAITV(n) asm volatile("s_waitcnt vmcnt(" #n ")" ::: "memory")

  bf16x8 aq0[2][2], aq1[2][2], bqX[4][2], bqY[4][2];
  f32x4 acc[8][4];
#pragma unroll
  for (int m = 0; m < 8; ++m)
#pragma unroll
    for (int n = 0; n < 4; ++n) acc[m][n] = (f32x4){0.f, 0.f, 0.f, 0.f};

  // prologue: X=buf0 full KT0; Y=buf1 gets KT1's B halves (A halves come ph1/ph2)
  STG_A(0, 0, 0); STG_A(0, 1, 0); STG_B(0, 0, 0); STG_B(0, 1, 0);
  STG_B(1, 0, 1); STG_B(1, 1, 1);
  WAITV(4);       // KT0 landed; Y.B (4) in flight
  BAR();
  // prefetch R(ph1): X m-pair0 + X B-set (12 reads)
  PREF_A(0, 0, aq0); PREF_B(0, bqX);
  SCB();

  for (int i = 0; i < NIT; ++i) {
    const bool g = (i < NIT - 1);
    const int kx = 2 * i + 2, ky = 2 * i + 3;
    // ---- ph1: MFMA X m0 (aq0,bqX); prefetch X m1 -> aq1; stage Y.A0 ----
    STG_A(1, 0, 2 * i + 1);
    BAR();
    PREF_A(0, 1, aq1); SCB();
    WAITL(4);
    MFMA16(aq0, bqX, 0);
    BAR();
    // ---- ph2: MFMA X m1; prefetch X m2 -> aq0; stage Y.A1, X'.B0 ----
    STG_A(1, 1, 2 * i + 1);
    if (g) STG_B(0, 0, kx);
    BAR();
    PREF_A(0, 2, aq0); SCB();
    WAITL(4);
    MFMA16(aq1, bqX, 1);
    BAR();
    // ---- ph3: MFMA X m2; prefetch X m3 -> aq1; stage X'.B1 ----
    if (g) STG_B(0, 1, kx);
    BAR();
    PREF_A(0, 3, aq1); SCB();
    WAITL(4);
    MFMA16(aq0, bqX, 2);
    BAR();
    // ---- ph4: vmcnt: Y complete; MFMA X m3; prefetch Y m0 + Y B ----
    if (g) WAITV(4); else WAITV(0);
    BAR();
    PREF_A(1, 0, aq0); PREF_B(1, bqY); SCB();
    WAITL(12);
    MFMA16(aq1, bqX, 3);
    BAR();
    // ---- ph5: MFMA Y m0 (aq0,bqY); prefetch Y m1 -> aq1; stage X'.A ----
    if (g) { STG_A(0, 0, kx); STG_A(0, 1, kx); }
    BAR();
    PREF_A(1, 1, aq1); SCB();
    WAITL(4);
    MFMA16(aq0, bqY, 0);
    BAR();
    // ---- ph6: MFMA Y m1; prefetch Y m2 -> aq0; stage Y'.B0 ----
    if (g) STG_B(1, 0, ky);
    BAR();
    PREF_A(1, 2, aq0); SCB();
    WAITL(4);
    MFMA16(aq1, bqY, 1);
    BAR();
    // ---- ph7: MFMA Y m2; prefetch Y m3 -> aq1; stage Y'.B1 ----
    if (g) STG_B(1, 1, ky);
    BAR();
    PREF_A(1, 3, aq1); SCB();
    WAITL(4);
    MFMA16(aq0, bqY, 2);
    BAR();
    // ---- ph8: vmcnt: X' complete; MFMA Y m3; prefetch X' m0 + X' B ----
    if (g) WAITV(4);
    BAR();
    if (g) {
      PREF_A(0, 0, aq0); PREF_B(0, bqX); SCB();
      WAITL(12);
    } else {
      WAITL(0);
    }
    MFMA16(aq1, bqY, 3);
    BAR();
  }
#undef STG_A
#undef STG_B
#undef PREF_A
#undef PREF_B

  // ===== epilogue: g = relu(acc+b1) -> LDS [256][256] bf16 (swizzled), then g x V^T =====
#pragma unroll
  for (int n = 0; n < 4; ++n) {
    const int lcol = wc * 64 + n * 16 + fr;
    const float bias = b1[(size_t)e * kH + bcol + lcol];
    const int cbyte = (lcol >> 3) << 4;
#pragma unroll
    for (int m = 0; m < 8; ++m) {
#pragma unroll
      for (int j = 0; j < 4; ++j) {
        const int lrow = wr * 128 + m * 16 + jg * 4 + j;
        const float v = fmaxf(acc[m][n][j] + bias, 0.f);
        *reinterpret_cast<unsigned short*>(
            smem + lrow * 512 + (cbyte ^ ((lrow & 7) << 4)) + (fr & 7) * 2) = f2bf(v);
      }
    }
  }
  asm volatile("s_waitcnt lgkmcnt(0)\ns_barrier" ::: "memory");

  // small GEMM: 16 row-groups of 16; contract 256 h-cols (8 x K32) with Vt
  const unsigned short* const VtE = Vt + (size_t)e * 16 * kH + (size_t)fr * kH + bcol;
  bf16x8 gv[8];
#pragma unroll
  for (int kk = 0; kk < 8; ++kk)
    gv[kk] = *reinterpret_cast<const bf16x8*>(VtE + kk * 32 + jg * 8);
#pragma unroll
  for (int f = 0; f < 2; ++f) {
    const int rowl = (2 * w + f) * 16 + fr;
    f32x4 pc = (f32x4){0.f, 0.f, 0.f, 0.f};
#pragma unroll
    for (int kk = 0; kk < 8; ++kk) {
      bf16x8 ga = *reinterpret_cast<const bf16x8*>(
          smem + rowl * 512 + ((((kk * 4 + jg)) ^ (rowl & 7)) << 4));
      pc = __builtin_amdgcn_mfma_f32_16x16x32_bf16(ga, gv[kk], pc, 0, 0, 0);
    }
    const int rowg = brow + (2 * w + f) * 16 + jg * 4;
#pragma unroll
    for (int j = 0; j < 4; ++j) {
      const float val = pc[j] * rr[(size_t)(rowg + j) * kE + e];
      atomicAdd(&part[(size_t)(rowg + j) * 16 + fr], val);
    }
  }
#undef MFMA16
#undef BAR
#undef SCB
#undef WAITL
#undef WAITV
}

// ------- combine: y[b][c] = part[b][c] + sum_e r[b][e]*u[e][c] + bc[c] -------
__global__ __launch_bounds__(256) void k_combine(const float* __restrict__ part,
                                                 const float* __restrict__ rr,
                                                 const float* __restrict__ u,
                                                 const float* __restrict__ bc,
                                                 float* __restrict__ y) {
  const int tid = threadIdx.x;
  const int rloc = tid >> 4, c = tid & 15;
  const int b = blockIdx.x * 16 + rloc;
  if (c >= kC) return;
  float acc = part[(size_t)b * 16 + c] + bc[c];
#pragma unroll
  for (int e = 0; e < kE; ++e) acc += rr[(size_t)b * kE + e] * u[e * 16 + c];
  y[(size_t)b * kC + c] = acc;
}

extern "C" void kernel_launch(void* const* d_in, const int* in_sizes, int n_in,
                              void* d_out, int out_size, void* d_ws, size_t ws_size,
                              hipStream_t stream) {
  (void)in_sizes; (void)n_in; (void)out_size; (void)ws_size;
  const float* x  = (const float*)d_in[0];
  const float* Wr = (const float*)d_in[1];
  const float* br = (const float*)d_in[2];
  const float* W1 = (const float*)d_in[3];
  const float* b1 = (const float*)d_in[4];
  const float* W2 = (const float*)d_in[5];
  const float* b2 = (const float*)d_in[6];
  const float* Wc = (const float*)d_in[7];
  const float* bc = (const float*)d_in[8];
  float* y = (float*)d_out;

  // workspace carve (~82 MB)
  char* p = (char*)d_ws;
  unsigned short* xb  = (unsigned short*)p; p += (size_t)kB * kD * 2;        // 16 MB
  unsigned short* W1t = (unsigned short*)p; p += (size_t)kE * kH * kD * 2;   // 64 MB
  unsigned short* Vt  = (unsigned short*)p; p += (size_t)kE * 16 * kH * 2;   // 1 MB
  float* r    = (float*)p;                  p += (size_t)kB * kE * 4;        // 256 KB
  float* u    = (float*)p;                  p += (size_t)kE * 16 * 4;        // 512 B
  float* part = (float*)p;                  p += (size_t)kB * 16 * 4;        // 512 KB

  k_convert_x<<<dim3(kB * kD / 8 / 256), dim3(256), 0, stream>>>(x, xb);
  k_routing<<<dim3(kB / 4), dim3(256), 0, stream>>>(x, Wr, br, r);
  k_transpose_w<<<dim3(kH / 32, kD / 32, kE), dim3(32, 8), 0, stream>>>(W1, W1t, kD, kH);
  k_vbuild<<<dim3(kE * kH / 128), dim3(128), 0, stream>>>(W2, Wc, Vt);
  k_ubuild<<<dim3(1), dim3(128), 0, stream>>>(b2, Wc, u);
  k_zero_f32<<<dim3(kB * 16 / 256), dim3(256), 0, stream>>>(part);

  k_moe_fused256<<<dim3(kB / 256, kH / 256, kE), dim3(512), 0, stream>>>(
      xb, W1t, b1, Vt, r, part);

  k_combine<<<dim3(kB / 16), dim3(256), 0, stream>>>(part, r, u, bc, y);
}